// Round 1
// baseline (1086.085 us; speedup 1.0000x reference)
//
#include <hip/hip_runtime.h>
#include <hip/hip_bf16.h>
#include <math.h>

#define UCNT 50000
#define ICNT 25000
#define NNODE 75000
#define DDIM 64
#define BB 4096
#define EPS_C 0.2f
#define INV_TEMP 5.0f

__device__ __forceinline__ float wave_sum(float x) {
#pragma unroll
  for (int m = 32; m >= 1; m >>= 1) x += __shfl_xor(x, m, 64);
  return x;
}

// ---------------- init: zero counts, rowsums, accumulators ----------------
__global__ void init_kernel(int* __restrict__ counts, float* __restrict__ rowsum_u,
                            float* __restrict__ rowsum_i, float* __restrict__ accum) {
  int i = blockIdx.x * blockDim.x + threadIdx.x;
  if (i < NNODE) counts[i] = 0;
  if (i < BB) { rowsum_u[i] = 0.f; rowsum_i[i] = 0.f; }
  if (i < 2) accum[i] = 0.f;
}

// ---------------- histogram ----------------
__global__ void hist_kernel(const int* __restrict__ src, int* __restrict__ counts, int ne) {
  int i = blockIdx.x * blockDim.x + threadIdx.x;
  int stride = gridDim.x * blockDim.x;
  for (; i < ne; i += stride) atomicAdd(&counts[src[i]], 1);
}

// ---------------- exclusive scan over 75001 entries, single block ----------------
__global__ __launch_bounds__(1024) void scan_kernel(const int* __restrict__ counts,
                                                    int* __restrict__ row_ptr,
                                                    int* __restrict__ cursor, int n) {
  const int T = 1024;
  int t = threadIdx.x;
  int chunk = (n + T - 1) / T;
  int begin = min(t * chunk, n);
  int end = min(begin + chunk, n);
  int s = 0;
  for (int i = begin; i < end; ++i) s += counts[i];
  int lane = t & 63, wid = t >> 6;
  int v = s;
#pragma unroll
  for (int d = 1; d < 64; d <<= 1) {
    int u = __shfl_up(v, d, 64);
    if (lane >= d) v += u;
  }
  __shared__ int wsum[16];
  if (lane == 63) wsum[wid] = v;
  __syncthreads();
  if (t == 0) {
    int run = 0;
    for (int k = 0; k < 16; ++k) { int tmp = wsum[k]; wsum[k] = run; run += tmp; }
  }
  __syncthreads();
  int excl = v - s + wsum[wid];
  int run = excl;
  for (int i = begin; i < end; ++i) {
    row_ptr[i] = run; cursor[i] = run; run += counts[i];
  }
  if (t == T - 1) row_ptr[n] = run;
}

// ---------------- scatter into CSR ----------------
__global__ void scatter_kernel(const int* __restrict__ src, const int* __restrict__ dst,
                               const float* __restrict__ val, int* __restrict__ cursor,
                               int* __restrict__ csr_dst, float* __restrict__ csr_val, int ne) {
  int i = blockIdx.x * blockDim.x + threadIdx.x;
  int stride = gridDim.x * blockDim.x;
  for (; i < ne; i += stride) {
    int slot = atomicAdd(&cursor[src[i]], 1);
    csr_dst[slot] = dst[i];
    csr_val[slot] = val[i];
  }
}

// ---------------- SpMM + noise perturbation, one wave per row ----------------
template <int FIRST>
__global__ __launch_bounds__(256) void spmm_kernel(const float* __restrict__ x_in,
                                                   const float* __restrict__ ut,
                                                   const float* __restrict__ it,
                                                   const int* __restrict__ row_ptr,
                                                   const int* __restrict__ csr_dst,
                                                   const float* __restrict__ csr_val,
                                                   const float* __restrict__ noise,
                                                   float* __restrict__ x_out) {
  int wave = blockIdx.x * (blockDim.x >> 6) + (threadIdx.x >> 6);
  int lane = threadIdx.x & 63;
  if (wave >= NNODE) return;
  int r = wave;
  int beg = row_ptr[r], endp = row_ptr[r + 1];
  float acc = 0.f;
  for (int e0 = beg; e0 < endp; e0 += 64) {
    int e = e0 + lane;
    int d = 0; float v = 0.f;
    if (e < endp) { d = csr_dst[e]; v = csr_val[e]; }
    int cnt = min(64, endp - e0);
    for (int j = 0; j < cnt; ++j) {
      int dj = __shfl(d, j, 64);
      float vj = __shfl(v, j, 64);
      const float* srcp;
      if (FIRST)
        srcp = (dj < UCNT) ? (ut + (size_t)dj * DDIM) : (it + (size_t)(dj - UCNT) * DDIM);
      else
        srcp = x_in + (size_t)dj * DDIM;
      acc += vj * srcp[lane];
    }
  }
  float nv = noise[(size_t)r * DDIM + lane];
  float ss = wave_sum(nv * nv);
  float nn = nv / fmaxf(sqrtf(ss), 1e-12f);
  float sgn = (acc > 0.f) ? 1.f : ((acc < 0.f) ? -1.f : 0.f);
  x_out[(size_t)r * DDIM + lane] = acc + sgn * nn * EPS_C;
}

// ---------------- batch gather: BPR, reg, normalized InfoNCE inputs ----------------
__global__ __launch_bounds__(256) void batch_kernel(
    const float* __restrict__ b0, const float* __restrict__ b1, const float* __restrict__ b2,
    const float* __restrict__ ut, const float* __restrict__ it,
    const int* __restrict__ user, const int* __restrict__ pos, const int* __restrict__ neg,
    float* __restrict__ z1u, float* __restrict__ z2u,
    float* __restrict__ z1i, float* __restrict__ z2i,
    float* __restrict__ pos_u, float* __restrict__ pos_i, float* __restrict__ accum) {
  int wave = blockIdx.x * (blockDim.x >> 6) + (threadIdx.x >> 6);
  int lane = threadIdx.x & 63;
  if (wave >= BB) return;
  int b = wave;
  int iu = user[b], ip = pos[b], ing = neg[b];
  size_t ru = (size_t)iu * DDIM + lane;
  size_t rp = (size_t)(UCNT + ip) * DDIM + lane;
  size_t rn = (size_t)(UCNT + ing) * DDIM + lane;
  float cu = b0[ru];               // x_cl user row
  float ci = b0[rp];               // x_cl positive-item row
  float ue = (cu + b1[ru] + b2[ru]) * (1.f / 3.f);
  float pe = (ci + b1[rp] + b2[rp]) * (1.f / 3.f);
  float ne = (b0[rn] + b1[rn] + b2[rn]) * (1.f / 3.f);

  float ps = wave_sum(ue * pe);
  float ns = wave_sum(ue * ne);
  float x = ns - ps;
  float sp = fmaxf(x, 0.f) + log1pf(expf(-fabsf(x)));

  float eu = ut[(size_t)iu * DDIM + lane];
  float ep = it[(size_t)ip * DDIM + lane];
  float en = it[(size_t)ing * DDIM + lane];
  float rr = wave_sum(eu * eu + ep * ep + en * en);
  if (lane == 0) { atomicAdd(&accum[0], sp); atomicAdd(&accum[1], rr); }

  float n1 = fmaxf(sqrtf(wave_sum(cu * cu)), 1e-12f);
  float n2 = fmaxf(sqrtf(wave_sum(ue * ue)), 1e-12f);
  float d12 = wave_sum(cu * ue);
  z1u[(size_t)b * DDIM + lane] = cu / n1;
  z2u[(size_t)b * DDIM + lane] = ue / n2;
  if (lane == 0) pos_u[b] = d12 / (n1 * n2) * INV_TEMP;

  float m1 = fmaxf(sqrtf(wave_sum(ci * ci)), 1e-12f);
  float m2 = fmaxf(sqrtf(wave_sum(pe * pe)), 1e-12f);
  float e12 = wave_sum(ci * pe);
  z1i[(size_t)b * DDIM + lane] = ci / m1;
  z2i[(size_t)b * DDIM + lane] = pe / m2;
  if (lane == 0) pos_i[b] = e12 / (m1 * m2) * INV_TEMP;
}

// ---------------- InfoNCE similarity tile: rowsum[i] += sum_j exp(5 * z1_i . z2_j) ----------------
__global__ __launch_bounds__(256) void infonce_kernel(const float* __restrict__ Z1,
                                                      const float* __restrict__ Z2,
                                                      float* __restrict__ rowsum) {
  __shared__ float S1[64][65];
  __shared__ float S2[64][65];
  __shared__ float red[64][17];
  int t = threadIdx.x;
  int i0 = blockIdx.y * 64, j0 = blockIdx.x * 64;
#pragma unroll
  for (int rep = 0; rep < 4; ++rep) {
    int vlin = rep * 256 + t;       // float4 index in 64x16
    int row = vlin >> 4;
    int c4 = (vlin & 15) * 4;
    float4 a = *(const float4*)(Z1 + (size_t)(i0 + row) * DDIM + c4);
    S1[c4 + 0][row] = a.x; S1[c4 + 1][row] = a.y; S1[c4 + 2][row] = a.z; S1[c4 + 3][row] = a.w;
    float4 b = *(const float4*)(Z2 + (size_t)(j0 + row) * DDIM + c4);
    S2[c4 + 0][row] = b.x; S2[c4 + 1][row] = b.y; S2[c4 + 2][row] = b.z; S2[c4 + 3][row] = b.w;
  }
  __syncthreads();
  int ti = (t & 15) * 4;
  int tj = (t >> 4) * 4;
  float acc[4][4] = {};
  for (int k = 0; k < 64; ++k) {
    float4 av = *(const float4*)&S1[k][ti];
    float4 bv = *(const float4*)&S2[k][tj];
    float a[4] = {av.x, av.y, av.z, av.w};
    float b[4] = {bv.x, bv.y, bv.z, bv.w};
#pragma unroll
    for (int r = 0; r < 4; ++r)
#pragma unroll
      for (int c = 0; c < 4; ++c) acc[r][c] += a[r] * b[c];
  }
  int q = t >> 4;
#pragma unroll
  for (int r = 0; r < 4; ++r) {
    float s = expf(acc[r][0] * INV_TEMP) + expf(acc[r][1] * INV_TEMP) +
              expf(acc[r][2] * INV_TEMP) + expf(acc[r][3] * INV_TEMP);
    red[ti + r][q] = s;
  }
  __syncthreads();
  if (t < 64) {
    float tot = 0.f;
#pragma unroll
    for (int q2 = 0; q2 < 16; ++q2) tot += red[t][q2];
    atomicAdd(&rowsum[i0 + t], tot);
  }
}

// ---------------- finalize ----------------
__global__ __launch_bounds__(256) void finalize_kernel(const float* __restrict__ rowsum_u,
                                                       const float* __restrict__ pos_u,
                                                       const float* __restrict__ rowsum_i,
                                                       const float* __restrict__ pos_i,
                                                       const float* __restrict__ accum,
                                                       float* __restrict__ out) {
  int t = threadIdx.x;
  float su = 0.f, si = 0.f;
  for (int i = t; i < BB; i += 256) {
    su += logf(rowsum_u[i]) - pos_u[i];
    si += logf(rowsum_i[i]) - pos_i[i];
  }
  su = wave_sum(su);
  si = wave_sum(si);
  __shared__ float sh[8];
  int lane = t & 63, wid = t >> 6;
  if (lane == 0) { sh[wid] = su; sh[4 + wid] = si; }
  __syncthreads();
  if (t == 0) {
    float SU = sh[0] + sh[1] + sh[2] + sh[3];
    float SI = sh[4] + sh[5] + sh[6] + sh[7];
    out[0] = accum[0] * (1.f / BB);
    out[1] = 1e-4f * 0.5f * accum[1] * (1.f / BB);
    out[2] = 0.2f * ((SU + SI) * (1.f / BB));
  }
}

extern "C" void kernel_launch(void* const* d_in, const int* in_sizes, int n_in,
                              void* d_out, int out_size, void* d_ws, size_t ws_size,
                              hipStream_t stream) {
  const float* user_table = (const float*)d_in[0];
  const float* item_table = (const float*)d_in[1];
  const float* edge_val   = (const float*)d_in[2];
  const float* noise      = (const float*)d_in[3];
  const int*   edge_src   = (const int*)d_in[4];
  const int*   edge_dst   = (const int*)d_in[5];
  const int*   user       = (const int*)d_in[6];
  const int*   positive   = (const int*)d_in[7];
  const int*   negative   = (const int*)d_in[8];
  const int E2 = in_sizes[2];  // 2,000,000

  char* w = (char*)d_ws;
  auto alloc = [&](size_t bytes) -> void* {
    void* p = (void*)w;
    w += (bytes + 255) & ~(size_t)255;
    return p;
  };
  int*   counts   = (int*)alloc((size_t)NNODE * 4);
  int*   row_ptr  = (int*)alloc((size_t)(NNODE + 1) * 4);
  int*   cursor   = (int*)alloc((size_t)NNODE * 4);
  int*   csr_dst  = (int*)alloc((size_t)E2 * 4);
  float* csr_val  = (float*)alloc((size_t)E2 * 4);
  float* buf0     = (float*)alloc((size_t)NNODE * DDIM * 4);
  float* buf1     = (float*)alloc((size_t)NNODE * DDIM * 4);
  float* buf2     = (float*)alloc((size_t)NNODE * DDIM * 4);
  float* z1u      = (float*)alloc((size_t)BB * DDIM * 4);
  float* z2u      = (float*)alloc((size_t)BB * DDIM * 4);
  float* z1i      = (float*)alloc((size_t)BB * DDIM * 4);
  float* z2i      = (float*)alloc((size_t)BB * DDIM * 4);
  float* pos_u    = (float*)alloc((size_t)BB * 4);
  float* pos_i    = (float*)alloc((size_t)BB * 4);
  float* rowsum_u = (float*)alloc((size_t)BB * 4);
  float* rowsum_i = (float*)alloc((size_t)BB * 4);
  float* accum    = (float*)alloc(256);

  init_kernel<<<(NNODE + 255) / 256, 256, 0, stream>>>(counts, rowsum_u, rowsum_i, accum);
  hist_kernel<<<2048, 256, 0, stream>>>(edge_src, counts, E2);
  scan_kernel<<<1, 1024, 0, stream>>>(counts, row_ptr, cursor, NNODE);
  scatter_kernel<<<2048, 256, 0, stream>>>(edge_src, edge_dst, edge_val, cursor,
                                           csr_dst, csr_val, E2);
  const int spmm_blocks = (NNODE + 3) / 4;  // 4 waves per 256-thread block
  spmm_kernel<1><<<spmm_blocks, 256, 0, stream>>>(nullptr, user_table, item_table, row_ptr,
                                                  csr_dst, csr_val,
                                                  noise + (size_t)0 * NNODE * DDIM, buf0);
  spmm_kernel<0><<<spmm_blocks, 256, 0, stream>>>(buf0, user_table, item_table, row_ptr,
                                                  csr_dst, csr_val,
                                                  noise + (size_t)1 * NNODE * DDIM, buf1);
  spmm_kernel<0><<<spmm_blocks, 256, 0, stream>>>(buf1, user_table, item_table, row_ptr,
                                                  csr_dst, csr_val,
                                                  noise + (size_t)2 * NNODE * DDIM, buf2);
  batch_kernel<<<BB / 4, 256, 0, stream>>>(buf0, buf1, buf2, user_table, item_table,
                                           user, positive, negative,
                                           z1u, z2u, z1i, z2i, pos_u, pos_i, accum);
  dim3 ig(BB / 64, BB / 64);
  infonce_kernel<<<ig, 256, 0, stream>>>(z1u, z2u, rowsum_u);
  infonce_kernel<<<ig, 256, 0, stream>>>(z1i, z2i, rowsum_i);
  finalize_kernel<<<1, 256, 0, stream>>>(rowsum_u, pos_u, rowsum_i, pos_i, accum,
                                         (float*)d_out);
}

// Round 2
// 740.782 us; speedup vs baseline: 1.4661x; 1.4661x over previous
//
#include <hip/hip_runtime.h>
#include <hip/hip_bf16.h>
#include <math.h>

#define UCNT 50000
#define ICNT 25000
#define NNODE 75000
#define DDIM 64
#define BB 4096
#define EPS_C 0.2f
#define INV_TEMP 5.0f
#define NB_SCAN ((NNODE + 255) / 256)   // 293

__device__ __forceinline__ float wave_sum(float x) {
#pragma unroll
  for (int m = 32; m >= 1; m >>= 1) x += __shfl_xor(x, m, 64);
  return x;
}

// ---------------- init: zero counts, rowsums, accumulators ----------------
__global__ void init_kernel(int* __restrict__ counts, float* __restrict__ rowsum_u,
                            float* __restrict__ rowsum_i, float* __restrict__ accum) {
  int i = blockIdx.x * blockDim.x + threadIdx.x;
  if (i < NNODE) counts[i] = 0;
  if (i < BB) { rowsum_u[i] = 0.f; rowsum_i[i] = 0.f; }
  if (i < 2) accum[i] = 0.f;
}

// ---------------- histogram ----------------
__global__ void hist_kernel(const int* __restrict__ src, int* __restrict__ counts, int ne) {
  int i = blockIdx.x * blockDim.x + threadIdx.x;
  int stride = gridDim.x * blockDim.x;
  for (; i < ne; i += stride) atomicAdd(&counts[src[i]], 1);
}

// ---------------- hierarchical scan: pass 1 — per-block sums ----------------
__global__ __launch_bounds__(256) void blocksum_kernel(const int* __restrict__ counts,
                                                       int* __restrict__ bsum, int n) {
  int t = threadIdx.x;
  int i = blockIdx.x * 256 + t;
  int c = (i < n) ? counts[i] : 0;
#pragma unroll
  for (int m = 32; m >= 1; m >>= 1) c += __shfl_xor(c, m, 64);
  __shared__ int ws[4];
  if ((t & 63) == 0) ws[t >> 6] = c;
  __syncthreads();
  if (t == 0) bsum[blockIdx.x] = ws[0] + ws[1] + ws[2] + ws[3];
}

// ---------------- hierarchical scan: pass 2 — scan the 293 block sums ----------------
__global__ __launch_bounds__(512) void bscan_kernel(const int* __restrict__ bsum,
                                                    int* __restrict__ boff, int nb) {
  int t = threadIdx.x;
  int lane = t & 63, wid = t >> 6;
  int c = (t < nb) ? bsum[t] : 0;
  int v = c;
#pragma unroll
  for (int d = 1; d < 64; d <<= 1) {
    int u = __shfl_up(v, d, 64);
    if (lane >= d) v += u;
  }
  __shared__ int ws[8], wo[8];
  if (lane == 63) ws[wid] = v;
  __syncthreads();
  if (t == 0) {
    int run = 0;
    for (int k = 0; k < 8; ++k) { wo[k] = run; run += ws[k]; }
  }
  __syncthreads();
  if (t < nb) boff[t] = v - c + wo[wid];
}

// ---------------- hierarchical scan: pass 3 — local scan + offset, write row_ptr/cursor --
__global__ __launch_bounds__(256) void scanout_kernel(const int* __restrict__ counts,
                                                      const int* __restrict__ boff,
                                                      int* __restrict__ row_ptr,
                                                      int* __restrict__ cursor, int n) {
  int t = threadIdx.x;
  int lane = t & 63, wid = t >> 6;
  int i = blockIdx.x * 256 + t;
  int c = (i < n) ? counts[i] : 0;
  int v = c;
#pragma unroll
  for (int d = 1; d < 64; d <<= 1) {
    int u = __shfl_up(v, d, 64);
    if (lane >= d) v += u;
  }
  __shared__ int ws[4], wo[4];
  if (lane == 63) ws[wid] = v;
  __syncthreads();
  if (t == 0) {
    int run = 0;
    for (int k = 0; k < 4; ++k) { wo[k] = run; run += ws[k]; }
  }
  __syncthreads();
  int excl = v - c + wo[wid] + boff[blockIdx.x];
  if (i < n) {
    row_ptr[i] = excl;
    cursor[i] = excl;
    if (i == n - 1) row_ptr[n] = excl + c;
  }
}

// ---------------- scatter into CSR ----------------
__global__ void scatter_kernel(const int* __restrict__ src, const int* __restrict__ dst,
                               const float* __restrict__ val, int* __restrict__ cursor,
                               int* __restrict__ csr_dst, float* __restrict__ csr_val, int ne) {
  int i = blockIdx.x * blockDim.x + threadIdx.x;
  int stride = gridDim.x * blockDim.x;
  for (; i < ne; i += stride) {
    int slot = atomicAdd(&cursor[src[i]], 1);
    csr_dst[slot] = dst[i];
    csr_val[slot] = val[i];
  }
}

// ---------------- SpMM + noise, one wave per row, 4 edges in flight ----------------
template <int FIRST>
__global__ __launch_bounds__(256) void spmm_kernel(const float* __restrict__ x_in,
                                                   const float* __restrict__ ut,
                                                   const float* __restrict__ it,
                                                   const int* __restrict__ row_ptr,
                                                   const int* __restrict__ csr_dst,
                                                   const float* __restrict__ csr_val,
                                                   const float* __restrict__ noise,
                                                   float* __restrict__ x_out) {
  int wave = blockIdx.x * 4 + (threadIdx.x >> 6);
  int lane = threadIdx.x & 63;
  if (wave >= NNODE) return;
  int r = wave;
  int beg = row_ptr[r], endp = row_ptr[r + 1];
  int g = lane >> 4, l16 = lane & 15;
  float4 acc = {0.f, 0.f, 0.f, 0.f};
  for (int e0 = beg; e0 < endp; e0 += 64) {
    int e = e0 + lane;
    int d = 0; float v = 0.f;
    if (e < endp) { d = csr_dst[e]; v = csr_val[e]; }
    int cnt = min(64, endp - e0);
    for (int j = 0; j < cnt; j += 4) {
      int dj = __shfl(d, j + g, 64);      // out-of-range sources carry v=0 -> harmless
      float vj = __shfl(v, j + g, 64);
      const float* srcp;
      if (FIRST)
        srcp = (dj < UCNT) ? (ut + (size_t)dj * DDIM) : (it + (size_t)(dj - UCNT) * DDIM);
      else
        srcp = x_in + (size_t)dj * DDIM;
      float4 xv = *(const float4*)(srcp + l16 * 4);
      acc.x += vj * xv.x; acc.y += vj * xv.y; acc.z += vj * xv.z; acc.w += vj * xv.w;
    }
  }
  // reduce the 4 edge-groups (lanes g=0..3 hold partial sums for same dims)
#pragma unroll
  for (int m = 16; m <= 32; m <<= 1) {
    acc.x += __shfl_xor(acc.x, m, 64);
    acc.y += __shfl_xor(acc.y, m, 64);
    acc.z += __shfl_xor(acc.z, m, 64);
    acc.w += __shfl_xor(acc.w, m, 64);
  }
  float4 nf = *(const float4*)(noise + (size_t)r * DDIM + l16 * 4);
  float ss = nf.x * nf.x + nf.y * nf.y + nf.z * nf.z + nf.w * nf.w;
#pragma unroll
  for (int m = 1; m <= 8; m <<= 1) ss += __shfl_xor(ss, m, 64);  // 16-lane group = full row
  float inv = EPS_C / fmaxf(sqrtf(ss), 1e-12f);
  float4 o;
  o.x = acc.x + ((acc.x > 0.f) ? 1.f : ((acc.x < 0.f) ? -1.f : 0.f)) * nf.x * inv;
  o.y = acc.y + ((acc.y > 0.f) ? 1.f : ((acc.y < 0.f) ? -1.f : 0.f)) * nf.y * inv;
  o.z = acc.z + ((acc.z > 0.f) ? 1.f : ((acc.z < 0.f) ? -1.f : 0.f)) * nf.z * inv;
  o.w = acc.w + ((acc.w > 0.f) ? 1.f : ((acc.w < 0.f) ? -1.f : 0.f)) * nf.w * inv;
  if (g == 0) *(float4*)(x_out + (size_t)r * DDIM + l16 * 4) = o;
}

// ---------------- batch gather: BPR, reg, normalized InfoNCE inputs ----------------
__global__ __launch_bounds__(256) void batch_kernel(
    const float* __restrict__ b0, const float* __restrict__ b1, const float* __restrict__ b2,
    const float* __restrict__ ut, const float* __restrict__ it,
    const int* __restrict__ user, const int* __restrict__ pos, const int* __restrict__ neg,
    float* __restrict__ z1u, float* __restrict__ z2u,
    float* __restrict__ z1i, float* __restrict__ z2i,
    float* __restrict__ pos_u, float* __restrict__ pos_i, float* __restrict__ accum) {
  int wave = blockIdx.x * (blockDim.x >> 6) + (threadIdx.x >> 6);
  int lane = threadIdx.x & 63;
  if (wave >= BB) return;
  int b = wave;
  int iu = user[b], ip = pos[b], ing = neg[b];
  size_t ru = (size_t)iu * DDIM + lane;
  size_t rp = (size_t)(UCNT + ip) * DDIM + lane;
  size_t rn = (size_t)(UCNT + ing) * DDIM + lane;
  float cu = b0[ru];               // x_cl user row
  float ci = b0[rp];               // x_cl positive-item row
  float ue = (cu + b1[ru] + b2[ru]) * (1.f / 3.f);
  float pe = (ci + b1[rp] + b2[rp]) * (1.f / 3.f);
  float ne = (b0[rn] + b1[rn] + b2[rn]) * (1.f / 3.f);

  float ps = wave_sum(ue * pe);
  float ns = wave_sum(ue * ne);
  float x = ns - ps;
  float sp = fmaxf(x, 0.f) + log1pf(expf(-fabsf(x)));

  float eu = ut[(size_t)iu * DDIM + lane];
  float ep = it[(size_t)ip * DDIM + lane];
  float en = it[(size_t)ing * DDIM + lane];
  float rr = wave_sum(eu * eu + ep * ep + en * en);
  if (lane == 0) { atomicAdd(&accum[0], sp); atomicAdd(&accum[1], rr); }

  float n1 = fmaxf(sqrtf(wave_sum(cu * cu)), 1e-12f);
  float n2 = fmaxf(sqrtf(wave_sum(ue * ue)), 1e-12f);
  float d12 = wave_sum(cu * ue);
  z1u[(size_t)b * DDIM + lane] = cu / n1;
  z2u[(size_t)b * DDIM + lane] = ue / n2;
  if (lane == 0) pos_u[b] = d12 / (n1 * n2) * INV_TEMP;

  float m1 = fmaxf(sqrtf(wave_sum(ci * ci)), 1e-12f);
  float m2 = fmaxf(sqrtf(wave_sum(pe * pe)), 1e-12f);
  float e12 = wave_sum(ci * pe);
  z1i[(size_t)b * DDIM + lane] = ci / m1;
  z2i[(size_t)b * DDIM + lane] = pe / m2;
  if (lane == 0) pos_i[b] = e12 / (m1 * m2) * INV_TEMP;
}

// ---------------- InfoNCE similarity tile: rowsum[i] += sum_j exp(5 * z1_i . z2_j) ----------------
__global__ __launch_bounds__(256) void infonce_kernel(const float* __restrict__ Z1,
                                                      const float* __restrict__ Z2,
                                                      float* __restrict__ rowsum) {
  __shared__ float S1[64][65];
  __shared__ float S2[64][65];
  __shared__ float red[64][17];
  int t = threadIdx.x;
  int i0 = blockIdx.y * 64, j0 = blockIdx.x * 64;
#pragma unroll
  for (int rep = 0; rep < 4; ++rep) {
    int vlin = rep * 256 + t;       // float4 index in 64x16
    int row = vlin >> 4;
    int c4 = (vlin & 15) * 4;
    float4 a = *(const float4*)(Z1 + (size_t)(i0 + row) * DDIM + c4);
    S1[c4 + 0][row] = a.x; S1[c4 + 1][row] = a.y; S1[c4 + 2][row] = a.z; S1[c4 + 3][row] = a.w;
    float4 b = *(const float4*)(Z2 + (size_t)(j0 + row) * DDIM + c4);
    S2[c4 + 0][row] = b.x; S2[c4 + 1][row] = b.y; S2[c4 + 2][row] = b.z; S2[c4 + 3][row] = b.w;
  }
  __syncthreads();
  int ti = (t & 15) * 4;
  int tj = (t >> 4) * 4;
  float acc[4][4] = {};
  for (int k = 0; k < 64; ++k) {
    float4 av = *(const float4*)&S1[k][ti];
    float4 bv = *(const float4*)&S2[k][tj];
    float a[4] = {av.x, av.y, av.z, av.w};
    float b[4] = {bv.x, bv.y, bv.z, bv.w};
#pragma unroll
    for (int r = 0; r < 4; ++r)
#pragma unroll
      for (int c = 0; c < 4; ++c) acc[r][c] += a[r] * b[c];
  }
  int q = t >> 4;
#pragma unroll
  for (int r = 0; r < 4; ++r) {
    float s = __expf(acc[r][0] * INV_TEMP) + __expf(acc[r][1] * INV_TEMP) +
              __expf(acc[r][2] * INV_TEMP) + __expf(acc[r][3] * INV_TEMP);
    red[ti + r][q] = s;
  }
  __syncthreads();
  if (t < 64) {
    float tot = 0.f;
#pragma unroll
    for (int q2 = 0; q2 < 16; ++q2) tot += red[t][q2];
    atomicAdd(&rowsum[i0 + t], tot);
  }
}

// ---------------- finalize ----------------
__global__ __launch_bounds__(256) void finalize_kernel(const float* __restrict__ rowsum_u,
                                                       const float* __restrict__ pos_u,
                                                       const float* __restrict__ rowsum_i,
                                                       const float* __restrict__ pos_i,
                                                       const float* __restrict__ accum,
                                                       float* __restrict__ out) {
  int t = threadIdx.x;
  float su = 0.f, si = 0.f;
  for (int i = t; i < BB; i += 256) {
    su += logf(rowsum_u[i]) - pos_u[i];
    si += logf(rowsum_i[i]) - pos_i[i];
  }
  su = wave_sum(su);
  si = wave_sum(si);
  __shared__ float sh[8];
  int lane = t & 63, wid = t >> 6;
  if (lane == 0) { sh[wid] = su; sh[4 + wid] = si; }
  __syncthreads();
  if (t == 0) {
    float SU = sh[0] + sh[1] + sh[2] + sh[3];
    float SI = sh[4] + sh[5] + sh[6] + sh[7];
    out[0] = accum[0] * (1.f / BB);
    out[1] = 1e-4f * 0.5f * accum[1] * (1.f / BB);
    out[2] = 0.2f * ((SU + SI) * (1.f / BB));
  }
}

extern "C" void kernel_launch(void* const* d_in, const int* in_sizes, int n_in,
                              void* d_out, int out_size, void* d_ws, size_t ws_size,
                              hipStream_t stream) {
  const float* user_table = (const float*)d_in[0];
  const float* item_table = (const float*)d_in[1];
  const float* edge_val   = (const float*)d_in[2];
  const float* noise      = (const float*)d_in[3];
  const int*   edge_src   = (const int*)d_in[4];
  const int*   edge_dst   = (const int*)d_in[5];
  const int*   user       = (const int*)d_in[6];
  const int*   positive   = (const int*)d_in[7];
  const int*   negative   = (const int*)d_in[8];
  const int E2 = in_sizes[2];  // 2,000,000

  char* w = (char*)d_ws;
  auto alloc = [&](size_t bytes) -> void* {
    void* p = (void*)w;
    w += (bytes + 255) & ~(size_t)255;
    return p;
  };
  int*   counts   = (int*)alloc((size_t)NNODE * 4);
  int*   row_ptr  = (int*)alloc((size_t)(NNODE + 1) * 4);
  int*   cursor   = (int*)alloc((size_t)NNODE * 4);
  int*   bsum     = (int*)alloc((size_t)NB_SCAN * 4);
  int*   boff     = (int*)alloc((size_t)NB_SCAN * 4);
  int*   csr_dst  = (int*)alloc((size_t)E2 * 4);
  float* csr_val  = (float*)alloc((size_t)E2 * 4);
  float* buf0     = (float*)alloc((size_t)NNODE * DDIM * 4);
  float* buf1     = (float*)alloc((size_t)NNODE * DDIM * 4);
  float* buf2     = (float*)alloc((size_t)NNODE * DDIM * 4);
  float* z1u      = (float*)alloc((size_t)BB * DDIM * 4);
  float* z2u      = (float*)alloc((size_t)BB * DDIM * 4);
  float* z1i      = (float*)alloc((size_t)BB * DDIM * 4);
  float* z2i      = (float*)alloc((size_t)BB * DDIM * 4);
  float* pos_u    = (float*)alloc((size_t)BB * 4);
  float* pos_i    = (float*)alloc((size_t)BB * 4);
  float* rowsum_u = (float*)alloc((size_t)BB * 4);
  float* rowsum_i = (float*)alloc((size_t)BB * 4);
  float* accum    = (float*)alloc(256);

  init_kernel<<<(NNODE + 255) / 256, 256, 0, stream>>>(counts, rowsum_u, rowsum_i, accum);
  hist_kernel<<<2048, 256, 0, stream>>>(edge_src, counts, E2);
  blocksum_kernel<<<NB_SCAN, 256, 0, stream>>>(counts, bsum, NNODE);
  bscan_kernel<<<1, 512, 0, stream>>>(bsum, boff, NB_SCAN);
  scanout_kernel<<<NB_SCAN, 256, 0, stream>>>(counts, boff, row_ptr, cursor, NNODE);
  scatter_kernel<<<2048, 256, 0, stream>>>(edge_src, edge_dst, edge_val, cursor,
                                           csr_dst, csr_val, E2);
  const int spmm_blocks = (NNODE + 3) / 4;  // 4 waves per 256-thread block
  spmm_kernel<1><<<spmm_blocks, 256, 0, stream>>>(nullptr, user_table, item_table, row_ptr,
                                                  csr_dst, csr_val,
                                                  noise + (size_t)0 * NNODE * DDIM, buf0);
  spmm_kernel<0><<<spmm_blocks, 256, 0, stream>>>(buf0, user_table, item_table, row_ptr,
                                                  csr_dst, csr_val,
                                                  noise + (size_t)1 * NNODE * DDIM, buf1);
  spmm_kernel<0><<<spmm_blocks, 256, 0, stream>>>(buf1, user_table, item_table, row_ptr,
                                                  csr_dst, csr_val,
                                                  noise + (size_t)2 * NNODE * DDIM, buf2);
  batch_kernel<<<BB / 4, 256, 0, stream>>>(buf0, buf1, buf2, user_table, item_table,
                                           user, positive, negative,
                                           z1u, z2u, z1i, z2i, pos_u, pos_i, accum);
  dim3 ig(BB / 64, BB / 64);
  infonce_kernel<<<ig, 256, 0, stream>>>(z1u, z2u, rowsum_u);
  infonce_kernel<<<ig, 256, 0, stream>>>(z1i, z2i, rowsum_i);
  finalize_kernel<<<1, 256, 0, stream>>>(rowsum_u, pos_u, rowsum_i, pos_i, accum,
                                         (float*)d_out);
}